// Round 9
// baseline (748.784 us; speedup 1.0000x reference)
//
#include <hip/hip_runtime.h>
#include <hip/hip_cooperative_groups.h>

namespace cg = cooperative_groups;

// FNO2d "kinet" forward. BS=2, H=W=24, WIDTH=20, M1=M2=12, N=576, NPAIR=165600.
// Round-9: single cooperative kernel (grid.sync between phases) with NB=256
// (1 block/CU — always co-resident; round-8's NB=512 was likely rejected at
// launch: hipErrorCooperativeLaunchTooLarge -> silent zero output since the
// return code wasn't checked). Now checked, with fallback to the verified
// round-7 multi-kernel path.

#define N_     576
#define NPAIR_ 165600
#define C_     20
#define NB     256
#define NT     256
#define NB_TR  1294   // ceil(2*NPAIR/256) for fallback k_pre

__device__ __forceinline__ float gelu_f(float x){
    return 0.5f * x * (1.0f + erff(x * 0.70710678118654752440f));
}

// ============================ mega (cooperative) ============================
__global__ void __launch_bounds__(NT, 2)
k_mega(const float* __restrict__ rvi,  const float* __restrict__ xin,
       const float* __restrict__ fc0w, const float* __restrict__ fc0b,
       const float* __restrict__ scwr, const float* __restrict__ scwi,
       const float* __restrict__ wk,   const float* __restrict__ wb,
       const float* __restrict__ fc1w, const float* __restrict__ fc1b,
       const float* __restrict__ fc2w, const float* __restrict__ fc2b,
       const float* __restrict__ rs,
       float* __restrict__ rvt, float* __restrict__ x_cur,
       float* __restrict__ p_t, float* __restrict__ a_t,
       float* __restrict__ Xr,  float* __restrict__ Xi,
       float* __restrict__ vmax, float* __restrict__ out)
{
    cg::grid_group grid = cg::this_grid();
    __shared__ float sA[576], sB[288], sC[288], sD[288], sE[288];
    __shared__ float cst[24], snt[24];
    __shared__ short hlist[N_];
    __shared__ int   cnts[4];
    __shared__ float wacc[4][C_];
    __shared__ float prow[C_], arow[C_];
    __shared__ float wred[4];
    __shared__ float psum[2];

    const int tid = threadIdx.x;
    const int bid = blockIdx.x;
    const int wid = tid>>6, lane = tid&63;
    const float sl0 = rs[0], sl1 = rs[1], sl2 = rs[2], sl3 = rs[3];

    if (tid < 24){
        float s, c;
        sincosf((float)tid * 0.26179938779914943654f, &s, &c);  // 2*pi/24
        cst[tid]=c; snt[tid]=s;
    }
    __syncthreads();

    // ---- pre: rv_init transpose [b][c][pr] -> [b][pr][20]  +  lift ----
    for (int t = bid*NT + tid; t < 2*NPAIR_; t += NB*NT){
        int bb = t / NPAIR_, pr = t % NPAIR_;
        size_t ibase = (size_t)bb*C_*NPAIR_ + pr;
        float v[C_];
        #pragma unroll
        for (int c=0;c<C_;c++) v[c] = rvi[ibase + (size_t)c*NPAIR_];
        float4* dst = (float4*)(rvt + (size_t)t*C_);
        #pragma unroll
        for (int q=0;q<5;q++) dst[q] = make_float4(v[4*q],v[4*q+1],v[4*q+2],v[4*q+3]);
    }
    if (bid >= NB-5){
        int t = (bid-(NB-5))*NT + tid;
        if (t < 2*N_){
            int hw = t % N_;
            int h = hw/24, wc2 = hw%24;
            float in[12];
            const float* xp = xin + (size_t)t*10;
            #pragma unroll
            for (int q=0;q<10;q++) in[q]=xp[q];
            in[10] = (float)h   * (1.0f/23.0f);
            in[11] = (float)wc2 * (1.0f/23.0f);
            #pragma unroll
            for (int c=0;c<C_;c++){
                float acc = fc0b[c];
                #pragma unroll
                for (int q=0;q<12;q++) acc += in[q]*fc0w[q*C_+c];
                x_cur[(size_t)(t/N_)*C_*N_ + (size_t)c*N_ + hw] = acc;
            }
        }
    }
    grid.sync();

    for (int kk=0; kk<4; ++kk){
        const float* wkk = wk + kk*400;
        const float* wbk = wb + kk*20;
        const float* wrk = scwr + (size_t)kk*115200;   // 2*20*20*144
        const float* wik = scwi + (size_t)kk*115200;

        // ---- P1: forward DFT per (b,c) on blocks 0..39; p_t on last 5 blocks ----
        if (bid < 40){
            for (int q=tid;q<576;q+=NT) sA[q] = x_cur[(size_t)bid*576+q];
            __syncthreads();
            for (int idx=tid; idx<288; idx+=NT){      // stage 1: along w
                int h=idx/12, ky=idx%12;
                float ar=0.f, ai=0.f;
                for (int w=0;w<24;w++){
                    int m=(ky*w)%24;
                    float v=sA[h*24+w];
                    ar += v*cst[m];
                    ai -= v*snt[m];
                }
                sB[idx]=ar; sC[idx]=ai;
            }
            __syncthreads();
            for (int idx=tid; idx<288; idx+=NT){      // stage 2: along h
                int kx=idx/12, ky=idx%12;
                float ar=0.f, ai=0.f;
                for (int h=0;h<24;h++){
                    int m=(kx*h)%24;
                    float tr=sB[h*12+ky], ti=sC[h*12+ky];
                    float cc=cst[m], ss=snt[m];
                    ar += tr*cc + ti*ss;
                    ai += ti*cc - tr*ss;
                }
                Xr[(size_t)bid*288+idx]=ar;
                Xi[(size_t)bid*288+idx]=ai;
            }
        }
        if (bid >= NB-5){
            int t=(bid-(NB-5))*NT+tid;
            if (t < 2*N_){
                int bb=t/N_, hw=t%N_;
                float xi20[C_];
                #pragma unroll
                for (int c=0;c<C_;c++) xi20[c]=x_cur[(size_t)(bb*C_+c)*N_+hw];
                float accv[C_];
                #pragma unroll
                for (int o=0;o<C_;o++){
                    float acc=wbk[o];
                    #pragma unroll
                    for (int c=0;c<C_;c++) acc += xi20[c]*wkk[o*C_+c];
                    accv[o]=acc;
                }
                float4* dst=(float4*)(p_t+(size_t)t*C_);
                #pragma unroll
                for (int q=0;q<5;q++) dst[q]=make_float4(accv[4*q],accv[4*q+1],accv[4*q+2],accv[4*q+3]);
            }
        }
        grid.sync();

        // ---- P2: mode-mix + inverse FFT per (b,o) on blocks 0..39 ----
        if (bid < 40){
            int bb=bid/20, o=bid%20;
            for (int idx=tid; idx<288; idx+=NT){
                int ky=idx%12, kx=idx/12;
                int half=(kx>=12)?1:0; int mx=kx-half*12;
                float ar=0.f, ai=0.f;
                for (int i2=0;i2<20;i2++){
                    float xr =Xr[(size_t)(bb*20+i2)*288+idx];
                    float xiv=Xi[(size_t)(bb*20+i2)*288+idx];
                    size_t widx=((((size_t)half*20+i2)*20+o)*12+mx)*12+ky;
                    float wrv=wrk[widx], wiv=wik[widx];
                    ar += xr*wrv - xiv*wiv;
                    ai += xr*wiv + xiv*wrv;
                }
                sB[idx]=ar; sC[idx]=ai;
            }
            __syncthreads();
            for (int idx=tid; idx<288; idx+=NT){      // ifft along kx
                int h=idx/12, ky=idx%12;
                float ar=0.f, ai=0.f;
                for (int kx=0;kx<24;kx++){
                    int m=(kx*h)%24;
                    float fr=sB[kx*12+ky], fi=sC[kx*12+ky];
                    ar += fr*cst[m] - fi*snt[m];
                    ai += fr*snt[m] + fi*cst[m];
                }
                sD[idx]=ar*(1.0f/24.0f); sE[idx]=ai*(1.0f/24.0f);
            }
            __syncthreads();
            for (int idx=tid; idx<576; idx+=NT){      // irfft along ky (imag ky=0 dropped)
                int h=idx/24, w=idx%24;
                float acc=sD[h*12];
                #pragma unroll
                for (int ky=1;ky<12;ky++){
                    int m=(ky*w)%24;
                    acc += 2.0f*(sD[h*12+ky]*cst[m] - sE[h*12+ky]*snt[m]);
                }
                a_t[((size_t)bb*N_+idx)*C_+o] = acc*(1.0f/24.0f);
            }
        }
        grid.sync();

        // ---- P3: per-batch global max of v_r ----
        for (int row=bid; row<2*N_; row+=NB){
            int bb=row/N_, i=row%N_;
            if (tid<C_) arow[tid]=a_t[((size_t)bb*N_+i)*C_+tid];
            __syncthreads();
            const float4* abase=(const float4*)(a_t+(size_t)bb*N_*C_);
            float mloc=0.f;
            for (int j=tid;j<N_;j+=NT){
                const float4* aj=abase+j*5;
                float ssv=0.f;
                #pragma unroll
                for (int q=0;q<5;q++){
                    float4 av=aj[q];
                    float dv;
                    dv=arow[4*q+0]-av.x; ssv+=dv*dv;
                    dv=arow[4*q+1]-av.y; ssv+=dv*dv;
                    dv=arow[4*q+2]-av.z; ssv+=dv*dv;
                    dv=arow[4*q+3]-av.w; ssv+=dv*dv;
                }
                mloc=fmaxf(mloc, sqrtf(ssv+1e-12f));
            }
            #pragma unroll
            for (int off=32; off; off>>=1) mloc=fmaxf(mloc,__shfl_down(mloc,off,64));
            if (lane==0) wred[wid]=mloc;
            __syncthreads();
            if (tid==0){
                float mm=fmaxf(fmaxf(wred[0],wred[1]),fmaxf(wred[2],wred[3]));
                atomicMax((unsigned int*)&vmax[2*kk+bb], __float_as_uint(mm));
            }
            __syncthreads();
        }
        grid.sync();

        // ---- P4: collision update (+ fused head on kk==3) ----
        for (int row=bid; row<2*N_; row+=NB){
            int bb=row/N_, i=row%N_;
            if (tid<C_){
                prow[tid]=p_t[((size_t)bb*N_+i)*C_+tid];
                arow[tid]=a_t[((size_t)bb*N_+i)*C_+tid];
            }
            __syncthreads();
            float vm = vmax[2*kk+bb];
            const float thr = 0.1f;                  // f32(1.0 - 0.9), JAX weak-type
            const float4* pbase=(const float4*)(p_t+(size_t)bb*N_*C_);
            const float4* abase=(const float4*)(a_t+(size_t)bb*N_*C_);
            int jb=wid*144;
            unsigned long long m0,m1,m2;
            {
                auto test=[&](int j)->bool{
                    const float4* pj=pbase+j*5;
                    const float4* aj=abase+j*5;
                    float ssx=0.f, ssv=0.f;
                    #pragma unroll
                    for (int q=0;q<5;q++){
                        float4 pv=pj[q], av=aj[q];
                        float dx,dv;
                        dx=prow[4*q+0]-pv.x; dv=arow[4*q+0]-av.x; ssx+=dx*dx; ssv+=dv*dv;
                        dx=prow[4*q+1]-pv.y; dv=arow[4*q+1]-av.y; ssx+=dx*dx; ssv+=dv*dv;
                        dx=prow[4*q+2]-pv.z; dv=arow[4*q+2]-av.z; ssx+=dx*dx; ssv+=dv*dv;
                        dx=prow[4*q+3]-pv.w; dv=arow[4*q+3]-av.w; ssx+=dx*dx; ssv+=dv*dv;
                    }
                    float vrv=sqrtf(ssv+1e-12f);
                    float uxv=expf(-sqrtf(ssx+1e-12f));
                    return ((vrv/vm)*uxv > thr) && (j != i);
                };
                int j=jb+lane;
                m0=__ballot(test(j));
                m1=__ballot(test(j+64));
                bool h2=(lane<16)?test(jb+128+lane):false;
                m2=__ballot(h2);
            }
            if (lane==0) cnts[wid]=(int)(__popcll(m0)+__popcll(m1)+__popcll(m2));
            __syncthreads();
            int off0=0;
            #pragma unroll
            for (int w2=0;w2<4;w2++) if (w2<wid) off0+=cnts[w2];
            int nhit=cnts[0]+cnts[1]+cnts[2]+cnts[3];
            {
                unsigned long long below=(1ULL<<lane)-1ULL;
                int base=off0;
                if (m0&(1ULL<<lane)) hlist[base+__popcll(m0&below)]=(short)(jb+lane);
                base+=(int)__popcll(m0);
                if (m1&(1ULL<<lane)) hlist[base+__popcll(m1&below)]=(short)(jb+64+lane);
                base+=(int)__popcll(m1);
                if (m2&(1ULL<<lane)) hlist[base+__popcll(m2&below)]=(short)(jb+128+lane);
            }
            __syncthreads();

            float macc[C_];                          // rA - 0.5*sum(a_q)
            #pragma unroll
            for (int c=0;c<C_;c++) macc[c]=0.f;
            for (int t=tid; t<nhit; t+=NT){
                int j=hlist[t];
                float ssv=0.f;
                {
                    const float4* aj=abase+j*5;
                    #pragma unroll
                    for (int q=0;q<5;q++){
                        float4 aa=aj[q];
                        float dv;
                        dv=arow[4*q+0]-aa.x; ssv+=dv*dv; macc[4*q+0]-=0.5f*aa.x;
                        dv=arow[4*q+1]-aa.y; ssv+=dv*dv; macc[4*q+1]-=0.5f*aa.y;
                        dv=arow[4*q+2]-aa.z; ssv+=dv*dv; macc[4*q+2]-=0.5f*aa.z;
                        dv=arow[4*q+3]-aa.w; ssv+=dv*dv; macc[4*q+3]-=0.5f*aa.w;
                    }
                }
                float vrij=sqrtf(ssv+1e-12f);
                float sgn=(j<i)?1.0f:-1.0f;          // R[c,j,i] sign
                int lo=(j<i)?j:i, hi=(j<i)?i:j;
                int pidx=lo*(2*N_-lo-1)/2+(hi-lo-1);
                float vrs=sgn*vrij;
                float st[C_];
                {
                    const float4* rp=(const float4*)(rvt+((size_t)bb*NPAIR_+pidx)*C_);
                    #pragma unroll
                    for (int q=0;q<5;q++){
                        float4 rr=rp[q];
                        st[4*q+0]=rr.x; st[4*q+1]=rr.y; st[4*q+2]=rr.z; st[4*q+3]=rr.w;
                    }
                }
                float ssq=0.f;
                #pragma unroll
                for (int c=0;c<C_;c++) ssq+=st[c]*st[c];
                float ini=1.0f/sqrtf(ssq);
                float orc[C_];
                #pragma unroll
                for (int c=0;c<C_;c++) orc[c]=st[c]*ini;
                for (int l=0;l<=kk;l++){
                    float s=(l==0)?sl0:((l==1)?sl1:((l==2)?sl2:sl3));
                    float nq=0.f;
                    #pragma unroll
                    for (int c=0;c<C_;c++){
                        float nv=st[c]*orc[c]+orc[c]+s;
                        st[c]=nv; nq+=nv*nv;
                    }
                    float inn=1.0f/sqrtf(nq);
                    #pragma unroll
                    for (int c=0;c<C_;c++) st[c]*=inn;
                }
                #pragma unroll
                for (int c=0;c<C_;c++) macc[c]+=vrs*st[c];
            }
            #pragma unroll
            for (int off2=32; off2; off2>>=1){
                #pragma unroll
                for (int c=0;c<C_;c++) macc[c]+=__shfl_xor(macc[c],off2,64);
            }
            if (lane==0){
                #pragma unroll
                for (int c=0;c<C_;c++) wacc[wid][c]=macc[c];
            }
            __syncthreads();
            if (kk<3){
                if (tid<C_){
                    int c=tid;
                    float msum=wacc[0][c]+wacc[1][c]+wacc[2][c]+wacc[3][c];
                    float vi=arow[c];
                    float vnew=vi+0.5f*(float)nhit*vi+msum;
                    float xn=prow[c]+vnew;
                    x_cur[(size_t)(bb*C_+c)*N_+i]=gelu_f(xn);
                }
                __syncthreads();
            } else {
                if (tid<C_){
                    int c=tid;
                    float msum=wacc[0][c]+wacc[1][c]+wacc[2][c]+wacc[3][c];
                    float vi=arow[c];
                    float vnew=vi+0.5f*(float)nhit*vi+msum;
                    sA[c]=prow[c]+vnew;              // layer 3: no gelu
                }
                __syncthreads();
                float g=0.f;
                if (tid<128){
                    float h=fc1b[tid];
                    #pragma unroll
                    for (int c=0;c<C_;c++) h+=sA[c]*fc1w[c*128+tid];
                    g=gelu_f(h)*fc2w[tid];
                    #pragma unroll
                    for (int off2=32; off2; off2>>=1) g+=__shfl_down(g,off2,64);
                    if (lane==0) psum[wid]=g;
                }
                __syncthreads();
                if (tid==0) out[row]=psum[0]+psum[1]+fc2b[0];
                __syncthreads();
            }
        }
        if (kk<3) grid.sync();
    }
}

// ===================== fallback path (round-7, verified) =====================
__global__ void k_pre(const float* __restrict__ rvi, float* __restrict__ rvt,
                      const float* __restrict__ xin, const float* __restrict__ w,
                      const float* __restrict__ b, float* __restrict__ xo){
    int bid = blockIdx.x;
    if (bid < NB_TR){
        int t = bid*256 + threadIdx.x;
        if (t >= 2*NPAIR_) return;
        int bb = t / NPAIR_; int pr = t % NPAIR_;
        size_t ibase = (size_t)bb*C_*NPAIR_ + pr;
        float v[C_];
        #pragma unroll
        for (int c=0;c<C_;c++) v[c] = rvi[ibase + (size_t)c*NPAIR_];
        float4* dst = (float4*)(rvt + (size_t)t*C_);
        #pragma unroll
        for (int q=0;q<5;q++) dst[q] = make_float4(v[4*q],v[4*q+1],v[4*q+2],v[4*q+3]);
    } else {
        int t = (bid-NB_TR)*256 + threadIdx.x;
        if (t >= 2*N_) return;
        int hw = t % N_;
        int h = hw / 24, wc = hw % 24;
        float in[12];
        const float* xp = xin + (size_t)t*10;
        #pragma unroll
        for (int q=0;q<10;q++) in[q] = xp[q];
        in[10] = (float)h  * (1.0f/23.0f);
        in[11] = (float)wc * (1.0f/23.0f);
        #pragma unroll
        for (int c=0;c<C_;c++){
            float acc = b[c];
            #pragma unroll
            for (int q=0;q<12;q++) acc += in[q]*w[q*C_+c];
            xo[(size_t)(t/N_)*C_*N_ + (size_t)c*N_ + hw] = acc;
        }
    }
}

__global__ void k_specp(const float* __restrict__ x, float* __restrict__ Xr, float* __restrict__ Xi,
                        const float* __restrict__ wk, const float* __restrict__ wb,
                        float* __restrict__ p_t){
    if (blockIdx.x < 40){
        __shared__ float xt[576], Tr[288], Ti[288], cst[24], snt[24];
        int bc = blockIdx.x;
        int tid = threadIdx.x;
        if (tid < 24){
            float s, c;
            sincosf((float)tid * 0.26179938779914943654f, &s, &c);
            cst[tid]=c; snt[tid]=s;
        }
        for (int q=tid;q<576;q+=288) xt[q] = x[(size_t)bc*576+q];
        __syncthreads();
        {
            int h = tid/12, ky = tid%12;
            float ar=0.f, ai=0.f;
            for (int w=0;w<24;w++){
                int m = (ky*w) % 24;
                float v = xt[h*24+w];
                ar += v*cst[m];
                ai -= v*snt[m];
            }
            Tr[tid]=ar; Ti[tid]=ai;
        }
        __syncthreads();
        {
            int kx = tid/12, ky = tid%12;
            float ar=0.f, ai=0.f;
            for (int h=0;h<24;h++){
                int m = (kx*h)%24;
                float tr=Tr[h*12+ky], ti=Ti[h*12+ky];
                float cc=cst[m], ss=snt[m];
                ar += tr*cc + ti*ss;
                ai += ti*cc - tr*ss;
            }
            Xr[(size_t)bc*288 + tid] = ar;
            Xi[(size_t)bc*288 + tid] = ai;
        }
    } else {
        __shared__ float swk[400], swb[C_];
        int tid = threadIdx.x;
        for (int q=tid;q<400;q+=288) swk[q]=wk[q];
        if (tid < C_) swb[tid]=wb[tid];
        __syncthreads();
        int t = (blockIdx.x-40)*288 + tid;
        if (t >= 2*N_) return;
        int bb = t / N_, hw = t % N_;
        float xi[C_];
        #pragma unroll
        for (int c=0;c<C_;c++) xi[c] = x[(size_t)(bb*C_+c)*N_+hw];
        float accv[C_];
        #pragma unroll
        for (int o=0;o<C_;o++){
            float acc = swb[o];
            #pragma unroll
            for (int c=0;c<C_;c++) acc += xi[c]*swk[o*C_+c];
            accv[o]=acc;
        }
        float4* dst = (float4*)(p_t + (size_t)t*C_);
        #pragma unroll
        for (int q=0;q<5;q++) dst[q] = make_float4(accv[4*q],accv[4*q+1],accv[4*q+2],accv[4*q+3]);
    }
}

__global__ void k_fft_inv(const float* __restrict__ Xr, const float* __restrict__ Xi,
                          const float* __restrict__ wr, const float* __restrict__ wi,
                          float* __restrict__ a_t){
    __shared__ float Fr[288], Fi[288], Yr[288], Yi[288], cst[24], snt[24];
    int bo = blockIdx.x; int bb = bo/20, o = bo%20;
    int tid = threadIdx.x;
    if (tid < 24){
        float s, c;
        sincosf((float)tid * 0.26179938779914943654f, &s, &c);
        cst[tid]=c; snt[tid]=s;
    }
    if (tid < 288){
        int ky = tid%12, kx = tid/12;
        int half = (kx>=12) ? 1 : 0; int mx = kx - half*12;
        float ar=0.f, ai=0.f;
        for (int i=0;i<20;i++){
            float xr = Xr[(size_t)(bb*20+i)*288 + tid];
            float xi = Xi[(size_t)(bb*20+i)*288 + tid];
            size_t widx = ((((size_t)half*20+i)*20+o)*12+mx)*12+ky;
            float wrv = wr[widx], wiv = wi[widx];
            ar += xr*wrv - xi*wiv;
            ai += xr*wiv + xi*wrv;
        }
        Fr[tid]=ar; Fi[tid]=ai;
    }
    __syncthreads();
    if (tid < 288){
        int h = tid/12;
        float ar=0.f, ai=0.f;
        for (int kx=0;kx<24;kx++){
            int m=(kx*h)%24;
            float fr=Fr[kx*12 + (tid%12)], fi=Fi[kx*12 + (tid%12)];
            ar += fr*cst[m] - fi*snt[m];
            ai += fr*snt[m] + fi*cst[m];
        }
        Yr[tid]=ar*(1.0f/24.0f); Yi[tid]=ai*(1.0f/24.0f);
    }
    __syncthreads();
    {
        int h = tid/24, w = tid%24;
        float acc = Yr[h*12+0];
        #pragma unroll
        for (int ky=1;ky<12;ky++){
            int m=(ky*w)%24;
            acc += 2.0f*(Yr[h*12+ky]*cst[m] - Yi[h*12+ky]*snt[m]);
        }
        a_t[((size_t)bb*N_ + tid)*C_ + o] = acc*(1.0f/24.0f);
    }
}

__global__ void k_pairmax(const float* __restrict__ a_t, float* __restrict__ vmax){
    __shared__ float ai[C_], wred[9];
    int bb = blockIdx.x/N_, i = blockIdx.x%N_;
    int j = threadIdx.x;
    if (j < C_) ai[j]=a_t[((size_t)bb*N_+i)*C_+j];
    __syncthreads();
    const float4* aj4 = (const float4*)(a_t + ((size_t)bb*N_+j)*C_);
    float ssv=0.f;
    #pragma unroll
    for (int q=0;q<5;q++){
        float4 av = aj4[q];
        float dv;
        dv = ai[4*q+0]-av.x; ssv += dv*dv;
        dv = ai[4*q+1]-av.y; ssv += dv*dv;
        dv = ai[4*q+2]-av.z; ssv += dv*dv;
        dv = ai[4*q+3]-av.w; ssv += dv*dv;
    }
    float m = sqrtf(ssv+1e-12f);
    #pragma unroll
    for (int off=32; off; off>>=1) m = fmaxf(m, __shfl_down(m, off, 64));
    if ((j&63)==0) wred[j>>6] = m;
    __syncthreads();
    if (j==0){
        float mm = wred[0];
        #pragma unroll
        for (int q=1;q<9;q++) mm = fmaxf(mm, wred[q]);
        atomicMax((unsigned int*)&vmax[bb], __float_as_uint(mm));
    }
}

__global__ void __launch_bounds__(256, 1)
k_vnew(const float* __restrict__ p_t, const float* __restrict__ a_t,
       const float* __restrict__ rvt, const float* __restrict__ vmax,
       const float* __restrict__ rs, int klayer,
       float* __restrict__ xout, int do_gelu){
    __shared__ float pi[C_], ai[C_];
    __shared__ short hlist[N_];
    __shared__ int cnts[4];
    __shared__ float wacc[4][C_];
    int bb = blockIdx.x/N_, i = blockIdx.x%N_;
    int tid = threadIdx.x;
    int wid = tid>>6, lane = tid&63;
    if (tid < C_){ pi[tid]=p_t[((size_t)bb*N_+i)*C_+tid]; ai[tid]=a_t[((size_t)bb*N_+i)*C_+tid]; }
    __syncthreads();
    float vm = vmax[bb];
    const float thr = 0.1f;
    const float4* pbase = (const float4*)(p_t + (size_t)bb*N_*C_);
    const float4* abase = (const float4*)(a_t + (size_t)bb*N_*C_);

    int jb = wid*144;
    unsigned long long m0, m1, m2;
    {
        auto test = [&](int j)->bool{
            const float4* pj = pbase + j*5;
            const float4* aj = abase + j*5;
            float ssx=0.f, ssv=0.f;
            #pragma unroll
            for (int q=0;q<5;q++){
                float4 pv = pj[q], av = aj[q];
                float dx, dv;
                dx = pi[4*q+0]-pv.x; dv = ai[4*q+0]-av.x; ssx += dx*dx; ssv += dv*dv;
                dx = pi[4*q+1]-pv.y; dv = ai[4*q+1]-av.y; ssx += dx*dx; ssv += dv*dv;
                dx = pi[4*q+2]-pv.z; dv = ai[4*q+2]-av.z; ssx += dx*dx; ssv += dv*dv;
                dx = pi[4*q+3]-pv.w; dv = ai[4*q+3]-av.w; ssx += dx*dx; ssv += dv*dv;
            }
            float vrv = sqrtf(ssv+1e-12f);
            float uxv = expf(-sqrtf(ssx+1e-12f));
            return ((vrv/vm)*uxv > thr) && (j != i);
        };
        int j = jb + lane;
        m0 = __ballot(test(j));
        m1 = __ballot(test(j+64));
        bool h2 = (lane<16) ? test(jb+128+lane) : false;
        m2 = __ballot(h2);
    }
    if (lane == 0) cnts[wid] = (int)(__popcll(m0)+__popcll(m1)+__popcll(m2));
    __syncthreads();
    int off = 0;
    #pragma unroll
    for (int w=0;w<4;w++) if (w < wid) off += cnts[w];
    int nhit = cnts[0]+cnts[1]+cnts[2]+cnts[3];
    {
        unsigned long long below = (1ULL<<lane)-1ULL;
        int base = off;
        if (m0 & (1ULL<<lane)) hlist[base + __popcll(m0 & below)] = (short)(jb + lane);
        base += (int)__popcll(m0);
        if (m1 & (1ULL<<lane)) hlist[base + __popcll(m1 & below)] = (short)(jb + 64 + lane);
        base += (int)__popcll(m1);
        if (m2 & (1ULL<<lane)) hlist[base + __popcll(m2 & below)] = (short)(jb + 128 + lane);
    }
    __syncthreads();

    float s_arr[4] = { rs[0], rs[1], rs[2], rs[3] };
    float macc[C_];
    #pragma unroll
    for (int c=0;c<C_;c++) macc[c]=0.f;

    for (int t=tid; t<nhit; t+=256){
        int j = hlist[t];
        float av[C_];
        {
            const float4* aj = abase + j*5;
            #pragma unroll
            for (int q=0;q<5;q++){
                float4 aa = aj[q];
                av[4*q+0]=aa.x; av[4*q+1]=aa.y; av[4*q+2]=aa.z; av[4*q+3]=aa.w;
            }
        }
        float ssv=0.f;
        #pragma unroll
        for (int c=0;c<C_;c++){ float dv = ai[c]-av[c]; ssv += dv*dv; }
        float vrij = sqrtf(ssv+1e-12f);
        float sgn = (j<i) ? 1.0f : -1.0f;
        int lo = (j<i)?j:i, hi = (j<i)?i:j;
        int pidx = lo*(2*N_-lo-1)/2 + (hi-lo-1);
        float vrs = sgn*vrij;
        float st[C_];
        {
            const float4* rp = (const float4*)(rvt + ((size_t)bb*NPAIR_ + pidx)*C_);
            #pragma unroll
            for (int q=0;q<5;q++){
                float4 rr = rp[q];
                st[4*q+0]=rr.x; st[4*q+1]=rr.y; st[4*q+2]=rr.z; st[4*q+3]=rr.w;
            }
        }
        float ssq = 0.f;
        #pragma unroll
        for (int c=0;c<C_;c++) ssq += st[c]*st[c];
        float ini = 1.0f/sqrtf(ssq);
        float orc[C_];
        #pragma unroll
        for (int c=0;c<C_;c++) orc[c] = st[c]*ini;
        for (int l=0; l<=klayer; l++){
            float s = s_arr[l];
            float nq = 0.f;
            #pragma unroll
            for (int c=0;c<C_;c++){
                float nv = st[c]*orc[c] + orc[c] + s;
                st[c] = nv; nq += nv*nv;
            }
            float inn = 1.0f/sqrtf(nq);
            #pragma unroll
            for (int c=0;c<C_;c++) st[c] *= inn;
        }
        #pragma unroll
        for (int c=0;c<C_;c++) macc[c] += vrs*st[c] - 0.5f*av[c];
    }
    #pragma unroll
    for (int off2=32; off2; off2>>=1){
        #pragma unroll
        for (int c=0;c<C_;c++) macc[c] += __shfl_xor(macc[c], off2, 64);
    }
    if (lane == 0){
        #pragma unroll
        for (int c=0;c<C_;c++) wacc[wid][c] = macc[c];
    }
    __syncthreads();
    if (tid < C_){
        int c = tid;
        float msum = wacc[0][c]+wacc[1][c]+wacc[2][c]+wacc[3][c];
        float cnt = (float)nhit;
        float vi = ai[c];
        float vnew = vi + 0.5f*cnt*vi + msum;
        float xn = pi[c] + vnew;
        if (do_gelu) xn = gelu_f(xn);
        xout[(size_t)(bb*C_+c)*N_+i] = xn;
    }
}

__global__ void k_head(const float* __restrict__ x, const float* __restrict__ w1,
                       const float* __restrict__ b1, const float* __restrict__ w2,
                       const float* __restrict__ b2, float* __restrict__ out){
    __shared__ float xi[C_];
    __shared__ float part[2];
    int pos = blockIdx.x; int bb = pos/N_, hw = pos%N_;
    int t = threadIdx.x;
    if (t < C_) xi[t] = x[(size_t)(bb*C_+t)*N_+hw];
    __syncthreads();
    float h = b1[t];
    #pragma unroll
    for (int c=0;c<C_;c++) h += xi[c]*w1[c*128+t];
    float g = gelu_f(h) * w2[t];
    #pragma unroll
    for (int off=32; off; off>>=1) g += __shfl_down(g, off, 64);
    if ((t&63)==0) part[t>>6] = g;
    __syncthreads();
    if (t==0) out[pos] = part[0] + part[1] + b2[0];
}

extern "C" void kernel_launch(void* const* d_in, const int* in_sizes, int n_in,
                              void* d_out, int out_size, void* d_ws, size_t ws_size,
                              hipStream_t stream) {
    const float* in_x   = (const float*)d_in[0];
    const float* fc0_w  = (const float*)d_in[2];
    const float* fc0_b  = (const float*)d_in[3];
    const float* sc_wr  = (const float*)d_in[4];
    const float* sc_wi  = (const float*)d_in[5];
    const float* w_k    = (const float*)d_in[6];
    const float* w_b    = (const float*)d_in[7];
    const float* fc1_w  = (const float*)d_in[8];
    const float* fc1_b  = (const float*)d_in[9];
    const float* fc2_w  = (const float*)d_in[10];
    const float* fc2_b  = (const float*)d_in[11];
    const float* rv_init= (const float*)d_in[12];
    const float* rv_s   = (const float*)d_in[13];
    float* out = (float*)d_out;
    float* ws  = (float*)d_ws;

    float* rvt   = ws;                 // 6,624,000  [b][pair][20]
    float* x_cur = ws + 6624000;       // 23040      [b][c][n]
    float* p_t   = ws + 6647040;       // 23040      [b][n][20]
    float* a_t   = ws + 6670080;       // 23040      [b][n][20]
    float* Xr    = ws + 6693120;       // 11520
    float* Xi    = ws + 6704640;       // 11520
    float* vmax  = ws + 6716160;       // 8 = [4 layers][2 batches]

    hipMemsetAsync(vmax, 0, 8*sizeof(float), stream);

    void* args[] = {
        (void*)&rv_init, (void*)&in_x, (void*)&fc0_w, (void*)&fc0_b,
        (void*)&sc_wr, (void*)&sc_wi, (void*)&w_k, (void*)&w_b,
        (void*)&fc1_w, (void*)&fc1_b, (void*)&fc2_w, (void*)&fc2_b,
        (void*)&rv_s,
        (void*)&rvt, (void*)&x_cur, (void*)&p_t, (void*)&a_t,
        (void*)&Xr, (void*)&Xi, (void*)&vmax, (void*)&out
    };
    hipError_t err = hipLaunchCooperativeKernel((void*)k_mega, dim3(NB), dim3(NT), args, 0, stream);

    if (err != hipSuccess){
        // fallback: verified round-7 multi-kernel path
        k_pre<<<NB_TR+5, 256, 0, stream>>>(rv_init, rvt, in_x, fc0_w, fc0_b, x_cur);
        for (int k=0;k<4;k++){
            const size_t woff = (size_t)k*2*20*20*144;
            k_specp<<<44, 288, 0, stream>>>(x_cur, Xr, Xi, w_k + k*400, w_b + k*20, p_t);
            k_fft_inv<<<40, 576, 0, stream>>>(Xr, Xi, sc_wr+woff, sc_wi+woff, a_t);
            k_pairmax<<<2*N_, N_, 0, stream>>>(a_t, vmax + 2*k);
            k_vnew<<<2*N_, 256, 0, stream>>>(p_t, a_t, rvt, vmax + 2*k, rv_s, k, x_cur, (k<3) ? 1 : 0);
        }
        k_head<<<2*N_, 128, 0, stream>>>(x_cur, fc1_w, fc1_b, fc2_w, fc2_b, out);
    }
}

// Round 10
// 297.879 us; speedup vs baseline: 2.5137x; 2.5137x over previous
//
#include <hip/hip_runtime.h>

// FNO2d "kinet" forward. BS=2, H=W=24, WIDTH=20, M1=M2=12, N=576, NPAIR=165600.
// All f32. Output (2,24,24,1) flat = 1152 floats.
//
// Round-10: round-9 measured cooperative grid.sync at ~39us on MI355X (8
// non-coherent XCD L2s) -> mega-kernel abandoned. Multi-kernel path with
// fewer boundaries: spectral conv fully fused into ONE dispatch per layer
// (fwd DFT recomputed per output channel, ~1us VALU), head fused into the
// last collision kernel. 13 dispatches total (was 18).
//
// Collision algebra (verified round 2):
//   v_new[o] = v[o] + sum_q cmask[o,q] * [ (v[o]-v[q])/2 + vr[o,q]*R[c,q,o] ]
//   R[c,q,o] = +rv[pair(q,o)] if q<o else -rv[pair(o,q)].

#define N_     576
#define NPAIR_ 165600
#define C_     20
#define NB_TR  1294   // ceil(2*NPAIR/256)

__device__ __forceinline__ float gelu_f(float x){
    return 0.5f * x * (1.0f + erff(x * 0.70710678118654752440f));
}

// ---------- pre: rv_init transpose [b][c][pr] -> [b][pr][20]  +  lift ----------
__global__ void k_pre(const float* __restrict__ rvi, float* __restrict__ rvt,
                      const float* __restrict__ xin, const float* __restrict__ w,
                      const float* __restrict__ b, float* __restrict__ xo){
    int bid = blockIdx.x;
    if (bid < NB_TR){
        int t = bid*256 + threadIdx.x;
        if (t >= 2*NPAIR_) return;
        int bb = t / NPAIR_; int pr = t % NPAIR_;
        size_t ibase = (size_t)bb*C_*NPAIR_ + pr;
        float v[C_];
        #pragma unroll
        for (int c=0;c<C_;c++) v[c] = rvi[ibase + (size_t)c*NPAIR_];
        float4* dst = (float4*)(rvt + (size_t)t*C_);
        #pragma unroll
        for (int q=0;q<5;q++) dst[q] = make_float4(v[4*q],v[4*q+1],v[4*q+2],v[4*q+3]);
    } else {
        int t = (bid-NB_TR)*256 + threadIdx.x;
        if (t >= 2*N_) return;
        int hw = t % N_;
        int h = hw / 24, wc = hw % 24;
        float in[12];
        const float* xp = xin + (size_t)t*10;
        #pragma unroll
        for (int q=0;q<10;q++) in[q] = xp[q];
        in[10] = (float)h  * (1.0f/23.0f);
        in[11] = (float)wc * (1.0f/23.0f);
        #pragma unroll
        for (int c=0;c<C_;c++){
            float acc = b[c];
            #pragma unroll
            for (int q=0;q<12;q++) acc += in[q]*w[q*C_+c];
            xo[(size_t)(t/N_)*C_*N_ + (size_t)c*N_ + hw] = acc;
        }
    }
}

// ---------- fused spectral conv (blocks 0..39 = (b,o)) + p_t (blocks 40,41) ----------
// Per (b,o) block: for channel pairs (2it, 2it+1), halves of the block do
// stage-1/stage-2 DFT, accumulating X*W into F; then ifft(kx) + irfft(ky).
__global__ void __launch_bounds__(576, 1)
k_spec(const float* __restrict__ x, const float* __restrict__ wr, const float* __restrict__ wi,
       const float* __restrict__ wk, const float* __restrict__ wb,
       float* __restrict__ p_t, float* __restrict__ a_t){
    if (blockIdx.x < 40){
        __shared__ float cst[24], snt[24];
        __shared__ float xch[1152];          // 2 input channels; reused as Yr/Yi
        __shared__ float Tr[576], Ti[576];   // stage-1, 2 channels
        __shared__ float Fr[576], Fi[576];   // mode-mix accum, 2 halves
        int bb = blockIdx.x/20, o = blockIdx.x%20;
        int tid = threadIdx.x;
        int half2 = tid/288, t2 = tid%288;
        if (tid < 24){
            float s, c;
            sincosf((float)tid * 0.26179938779914943654f, &s, &c);  // 2*pi/24
            cst[tid]=c; snt[tid]=s;
        }
        Fr[tid]=0.f; Fi[tid]=0.f;
        __syncthreads();
        for (int it=0; it<10; ++it){
            for (int q=tid; q<1152; q+=576)
                xch[q] = x[((size_t)bb*C_ + 2*it + q/576)*N_ + (q%576)];
            __syncthreads();
            {   // stage 1 (along w) for channel 2it+half2
                int h=t2/12, ky=t2%12;
                const float* xc = xch + half2*576;
                float ar=0.f, ai=0.f;
                for (int w2=0;w2<24;w2++){
                    int m=(ky*w2)%24;
                    float v=xc[h*24+w2];
                    ar += v*cst[m];
                    ai -= v*snt[m];
                }
                Tr[half2*288+t2]=ar; Ti[half2*288+t2]=ai;
            }
            __syncthreads();
            {   // stage 2 (along h) + mode-mix accumulate
                int kx=t2/12, ky=t2%12;
                float ar=0.f, ai=0.f;
                for (int h=0;h<24;h++){
                    int m=(kx*h)%24;
                    float tr=Tr[half2*288+h*12+ky], ti=Ti[half2*288+h*12+ky];
                    float cc=cst[m], ss=snt[m];
                    ar += tr*cc + ti*ss;
                    ai += ti*cc - tr*ss;
                }
                int i2 = 2*it + half2;
                int hf=(kx>=12)?1:0; int mx=kx-hf*12;
                size_t widx=((((size_t)hf*20+i2)*20+o)*12+mx)*12+ky;
                float wrv=wr[widx], wiv=wi[widx];
                Fr[half2*288+t2] += ar*wrv - ai*wiv;
                Fi[half2*288+t2] += ar*wiv + ai*wrv;
            }
            __syncthreads();
        }
        if (tid<288){ Fr[tid]+=Fr[288+tid]; Fi[tid]+=Fi[288+tid]; }
        __syncthreads();
        if (tid<288){   // ifft along kx -> Y (into xch)
            int h=tid/12, ky=tid%12;
            float ar=0.f, ai=0.f;
            for (int kx=0;kx<24;kx++){
                int m=(kx*h)%24;
                float fr=Fr[kx*12+ky], fi=Fi[kx*12+ky];
                ar += fr*cst[m] - fi*snt[m];
                ai += fr*snt[m] + fi*cst[m];
            }
            xch[tid]=ar*(1.0f/24.0f); xch[288+tid]=ai*(1.0f/24.0f);
        }
        __syncthreads();
        {   // irfft along ky (imag of ky=0 discarded by irfft)
            int h=tid/24, w2=tid%24;
            float acc=xch[h*12];
            #pragma unroll
            for (int ky=1;ky<12;ky++){
                int m=(ky*w2)%24;
                acc += 2.0f*(xch[h*12+ky]*cst[m] - xch[288+h*12+ky]*snt[m]);
            }
            a_t[((size_t)bb*N_+tid)*C_+o] = acc*(1.0f/24.0f);
        }
    } else {
        __shared__ float swk[400], swb[C_];
        int tid = threadIdx.x;
        for (int q=tid;q<400;q+=576) swk[q]=wk[q];
        if (tid < C_) swb[tid]=wb[tid];
        __syncthreads();
        int t = (blockIdx.x-40)*576 + tid;            // (b,hw) < 1152
        if (t >= 2*N_) return;
        int bb = t / N_, hw = t % N_;
        float xi[C_];
        #pragma unroll
        for (int c=0;c<C_;c++) xi[c] = x[(size_t)(bb*C_+c)*N_+hw];
        float accv[C_];
        #pragma unroll
        for (int o=0;o<C_;o++){
            float acc = swb[o];
            #pragma unroll
            for (int c=0;c<C_;c++) acc += xi[c]*swk[o*C_+c];
            accv[o]=acc;
        }
        float4* dst = (float4*)(p_t + (size_t)t*C_);
        #pragma unroll
        for (int q=0;q<5;q++) dst[q] = make_float4(accv[4*q],accv[4*q+1],accv[4*q+2],accv[4*q+3]);
    }
}

// ---------------- v_r global max (v_r depends only on a) ----------------
__global__ void k_pairmax(const float* __restrict__ a_t, float* __restrict__ vmax){
    __shared__ float ai[C_], wred[9];
    int bb = blockIdx.x/N_, i = blockIdx.x%N_;
    int j = threadIdx.x;                         // 576 threads
    if (j < C_) ai[j]=a_t[((size_t)bb*N_+i)*C_+j];
    __syncthreads();
    const float4* aj4 = (const float4*)(a_t + ((size_t)bb*N_+j)*C_);
    float ssv=0.f;
    #pragma unroll
    for (int q=0;q<5;q++){
        float4 av = aj4[q];
        float dv;
        dv = ai[4*q+0]-av.x; ssv += dv*dv;
        dv = ai[4*q+1]-av.y; ssv += dv*dv;
        dv = ai[4*q+2]-av.z; ssv += dv*dv;
        dv = ai[4*q+3]-av.w; ssv += dv*dv;
    }
    float m = sqrtf(ssv+1e-12f);
    #pragma unroll
    for (int off=32; off; off>>=1) m = fmaxf(m, __shfl_down(m, off, 64));
    if ((j&63)==0) wred[j>>6] = m;
    __syncthreads();
    if (j==0){
        float mm = wred[0];
        #pragma unroll
        for (int q=1;q<9;q++) mm = fmaxf(mm, wred[q]);
        atomicMax((unsigned int*)&vmax[bb], __float_as_uint(mm));   // v_r >= 0
    }
}

// -------- collision update (+ fused output head on the last layer) --------
__global__ void __launch_bounds__(256, 1)
k_vnew(const float* __restrict__ p_t, const float* __restrict__ a_t,
       const float* __restrict__ rvt, const float* __restrict__ vmax,
       const float* __restrict__ rs, int klayer,
       float* __restrict__ xout, int do_head,
       const float* __restrict__ fc1w, const float* __restrict__ fc1b,
       const float* __restrict__ fc2w, const float* __restrict__ fc2b,
       float* __restrict__ out){
    __shared__ float pi[C_], ai[C_];
    __shared__ short hlist[N_];
    __shared__ int cnts[4];
    __shared__ float wacc[4][C_];
    __shared__ float xrow[C_];
    __shared__ float psum[2];
    int bb = blockIdx.x/N_, i = blockIdx.x%N_;
    int tid = threadIdx.x;
    int wid = tid>>6, lane = tid&63;
    if (tid < C_){ pi[tid]=p_t[((size_t)bb*N_+i)*C_+tid]; ai[tid]=a_t[((size_t)bb*N_+i)*C_+tid]; }
    __syncthreads();
    float vm = vmax[bb];
    const float thr = 0.1f;                      // f32(1.0 - 0.9), JAX weak-type
    const float4* pbase = (const float4*)(p_t + (size_t)bb*N_*C_);
    const float4* abase = (const float4*)(a_t + (size_t)bb*N_*C_);

    int jb = wid*144;
    unsigned long long m0, m1, m2;
    {
        auto test = [&](int j)->bool{
            const float4* pj = pbase + j*5;
            const float4* aj = abase + j*5;
            float ssx=0.f, ssv=0.f;
            #pragma unroll
            for (int q=0;q<5;q++){
                float4 pv = pj[q], av = aj[q];
                float dx, dv;
                dx = pi[4*q+0]-pv.x; dv = ai[4*q+0]-av.x; ssx += dx*dx; ssv += dv*dv;
                dx = pi[4*q+1]-pv.y; dv = ai[4*q+1]-av.y; ssx += dx*dx; ssv += dv*dv;
                dx = pi[4*q+2]-pv.z; dv = ai[4*q+2]-av.z; ssx += dx*dx; ssv += dv*dv;
                dx = pi[4*q+3]-pv.w; dv = ai[4*q+3]-av.w; ssx += dx*dx; ssv += dv*dv;
            }
            float vrv = sqrtf(ssv+1e-12f);
            float uxv = expf(-sqrtf(ssx+1e-12f));
            return ((vrv/vm)*uxv > thr) && (j != i);
        };
        int j = jb + lane;
        m0 = __ballot(test(j));
        m1 = __ballot(test(j+64));
        bool h2 = (lane<16) ? test(jb+128+lane) : false;
        m2 = __ballot(h2);
    }
    if (lane == 0) cnts[wid] = (int)(__popcll(m0)+__popcll(m1)+__popcll(m2));
    __syncthreads();
    int off = 0;
    #pragma unroll
    for (int w=0;w<4;w++) if (w < wid) off += cnts[w];
    int nhit = cnts[0]+cnts[1]+cnts[2]+cnts[3];
    {
        unsigned long long below = (1ULL<<lane)-1ULL;
        int base = off;
        if (m0 & (1ULL<<lane)) hlist[base + __popcll(m0 & below)] = (short)(jb + lane);
        base += (int)__popcll(m0);
        if (m1 & (1ULL<<lane)) hlist[base + __popcll(m1 & below)] = (short)(jb + 64 + lane);
        base += (int)__popcll(m1);
        if (m2 & (1ULL<<lane)) hlist[base + __popcll(m2 & below)] = (short)(jb + 128 + lane);
    }
    __syncthreads();

    float s_arr[4] = { rs[0], rs[1], rs[2], rs[3] };
    float macc[C_];                              // = rA - 0.5*sum(a_q)
    #pragma unroll
    for (int c=0;c<C_;c++) macc[c]=0.f;

    for (int t=tid; t<nhit; t+=256){
        int j = hlist[t];
        float av[C_];
        {
            const float4* aj = abase + j*5;
            #pragma unroll
            for (int q=0;q<5;q++){
                float4 aa = aj[q];
                av[4*q+0]=aa.x; av[4*q+1]=aa.y; av[4*q+2]=aa.z; av[4*q+3]=aa.w;
            }
        }
        float ssv=0.f;
        #pragma unroll
        for (int c=0;c<C_;c++){ float dv = ai[c]-av[c]; ssv += dv*dv; }
        float vrij = sqrtf(ssv+1e-12f);
        float sgn = (j<i) ? 1.0f : -1.0f;        // R[c,j,i] sign
        int lo = (j<i)?j:i, hi = (j<i)?i:j;
        int pidx = lo*(2*N_-lo-1)/2 + (hi-lo-1);
        float vrs = sgn*vrij;
        float st[C_];
        {
            const float4* rp = (const float4*)(rvt + ((size_t)bb*NPAIR_ + pidx)*C_);
            #pragma unroll
            for (int q=0;q<5;q++){
                float4 rr = rp[q];
                st[4*q+0]=rr.x; st[4*q+1]=rr.y; st[4*q+2]=rr.z; st[4*q+3]=rr.w;
            }
        }
        float ssq = 0.f;
        #pragma unroll
        for (int c=0;c<C_;c++) ssq += st[c]*st[c];
        float ini = 1.0f/sqrtf(ssq);
        float orc[C_];
        #pragma unroll
        for (int c=0;c<C_;c++) orc[c] = st[c]*ini;
        for (int l=0; l<=klayer; l++){
            float s = s_arr[l];
            float nq = 0.f;
            #pragma unroll
            for (int c=0;c<C_;c++){
                float nv = st[c]*orc[c] + orc[c] + s;
                st[c] = nv; nq += nv*nv;
            }
            float inn = 1.0f/sqrtf(nq);
            #pragma unroll
            for (int c=0;c<C_;c++) st[c] *= inn;
        }
        #pragma unroll
        for (int c=0;c<C_;c++) macc[c] += vrs*st[c] - 0.5f*av[c];
    }
    #pragma unroll
    for (int off2=32; off2; off2>>=1){
        #pragma unroll
        for (int c=0;c<C_;c++) macc[c] += __shfl_xor(macc[c], off2, 64);
    }
    if (lane == 0){
        #pragma unroll
        for (int c=0;c<C_;c++) wacc[wid][c] = macc[c];
    }
    __syncthreads();
    if (!do_head){
        if (tid < C_){
            int c = tid;
            float msum = wacc[0][c]+wacc[1][c]+wacc[2][c]+wacc[3][c];
            float vi = ai[c];
            float vnew = vi + 0.5f*(float)nhit*vi + msum;
            float xn = pi[c] + vnew;
            xout[(size_t)(bb*C_+c)*N_+i] = gelu_f(xn);   // channel-major for next layer
        }
    } else {
        if (tid < C_){
            int c = tid;
            float msum = wacc[0][c]+wacc[1][c]+wacc[2][c]+wacc[3][c];
            float vi = ai[c];
            float vnew = vi + 0.5f*(float)nhit*vi + msum;
            xrow[c] = pi[c] + vnew;                      // layer 3: no gelu
        }
        __syncthreads();
        if (tid < 128){
            float h = fc1b[tid];
            #pragma unroll
            for (int c=0;c<C_;c++) h += xrow[c]*fc1w[c*128+tid];
            float g = gelu_f(h)*fc2w[tid];
            #pragma unroll
            for (int off2=32; off2; off2>>=1) g += __shfl_down(g, off2, 64);
            if (lane==0) psum[wid] = g;
        }
        __syncthreads();
        if (tid==0) out[bb*N_+i] = psum[0] + psum[1] + fc2b[0];
    }
}

extern "C" void kernel_launch(void* const* d_in, const int* in_sizes, int n_in,
                              void* d_out, int out_size, void* d_ws, size_t ws_size,
                              hipStream_t stream) {
    const float* in_x   = (const float*)d_in[0];
    // d_in[1] (v) is dead in the reference forward
    const float* fc0_w  = (const float*)d_in[2];
    const float* fc0_b  = (const float*)d_in[3];
    const float* sc_wr  = (const float*)d_in[4];
    const float* sc_wi  = (const float*)d_in[5];
    const float* w_k    = (const float*)d_in[6];
    const float* w_b    = (const float*)d_in[7];
    const float* fc1_w  = (const float*)d_in[8];
    const float* fc1_b  = (const float*)d_in[9];
    const float* fc2_w  = (const float*)d_in[10];
    const float* fc2_b  = (const float*)d_in[11];
    const float* rv_init= (const float*)d_in[12];
    const float* rv_s   = (const float*)d_in[13];
    float* out = (float*)d_out;
    float* ws  = (float*)d_ws;

    // workspace layout (floats); total 6,693,128 floats = 26.8 MB
    float* rvt   = ws;                 // 6,624,000  [b][pair][20]
    float* x_cur = ws + 6624000;       // 23040      [b][c][n]
    float* p_t   = ws + 6647040;       // 23040      [b][n][20]
    float* a_t   = ws + 6670080;       // 23040      [b][n][20]
    float* vmax  = ws + 6693120;       // 8 = [4 layers][2 batches]

    hipMemsetAsync(vmax, 0, 8*sizeof(float), stream);

    k_pre<<<NB_TR+5, 256, 0, stream>>>(rv_init, rvt, in_x, fc0_w, fc0_b, x_cur);

    for (int k=0;k<4;k++){
        const size_t woff = (size_t)k*115200;  // 2*20*20*144
        k_spec<<<42, 576, 0, stream>>>(x_cur, sc_wr+woff, sc_wi+woff,
                                       w_k + k*400, w_b + k*20, p_t, a_t);
        k_pairmax<<<2*N_, N_, 0, stream>>>(a_t, vmax + 2*k);
        k_vnew<<<2*N_, 256, 0, stream>>>(p_t, a_t, rvt, vmax + 2*k, rv_s, k,
                                         x_cur, (k==3) ? 1 : 0,
                                         fc1_w, fc1_b, fc2_w, fc2_b, out);
    }
}

// Round 11
// 217.724 us; speedup vs baseline: 3.4391x; 1.3681x over previous
//
#include <hip/hip_runtime.h>

// FNO2d "kinet" forward. BS=2, H=W=24, WIDTH=20, M1=M2=12, N=576, NPAIR=165600.
// All f32. Output (2,24,24,1) flat = 1152 floats.
//
// Round-11: revert to round-7 per-layer split (4 small dispatches/layer —
// round 10 proved fusing them kills grid parallelism: 42-block k_spec was
// +69us). Additions: head fused into last k_vnew (validated round 10), and
// the 80MB rv_init transpose is spread as extra blocks across k_lift and the
// layer-0 kernels (those occupy <40 CUs; transpose streams on the idle CUs).
//
// Collision algebra (verified round 2):
//   v_new[o] = v[o] + sum_q cmask[o,q] * [ (v[o]-v[q])/2 + vr[o,q]*R[c,q,o] ]
//   R[c,q,o] = +rv[pair(q,o)] if q<o else -rv[pair(o,q)].

#define N_     576
#define NPAIR_ 165600
#define C_     20

// transpose chunk starts (pairs): lift 128x256, specp 384x288, inv 192x576, pmax 144x576
#define TR_LIFT_B 128
#define TR_SPEC_B 384
#define TR_INV_B  192
#define TR_PMAX_B 144
#define TR0 0
#define TR1 (TR0 + TR_LIFT_B*256)   // 32768
#define TR2 (TR1 + TR_SPEC_B*288)   // 143360
#define TR3 (TR2 + TR_INV_B*576)    // 253952

__device__ __forceinline__ float gelu_f(float x){
    return 0.5f * x * (1.0f + erff(x * 0.70710678118654752440f));
}

// transpose one pair-row: rv_init [b][c][pr] -> rvt [b][pr][20]
__device__ __forceinline__ void tr_one(const float* __restrict__ rvi,
                                       float* __restrict__ rvt, int t){
    if (t >= 2*NPAIR_) return;
    int bb = t / NPAIR_, pr = t % NPAIR_;
    size_t ibase = (size_t)bb*C_*NPAIR_ + pr;
    float v[C_];
    #pragma unroll
    for (int c=0;c<C_;c++) v[c] = rvi[ibase + (size_t)c*NPAIR_];
    float4* dst = (float4*)(rvt + (size_t)t*C_);
    #pragma unroll
    for (int q=0;q<5;q++) dst[q] = make_float4(v[4*q],v[4*q+1],v[4*q+2],v[4*q+3]);
}

// ---------------- lift (blocks 0..4) + transpose chunk (blocks 5..) ----------------
__global__ void k_lift(const float* __restrict__ xin, const float* __restrict__ w,
                       const float* __restrict__ b, float* __restrict__ xo,
                       const float* __restrict__ rvi, float* __restrict__ rvt){
    int bid = blockIdx.x;
    if (bid >= 5){
        tr_one(rvi, rvt, TR0 + (bid-5)*256 + (int)threadIdx.x);
        return;
    }
    int t = bid*256 + threadIdx.x;
    if (t >= 2*N_) return;
    int hw = t % N_;
    int h = hw / 24, wc = hw % 24;
    float in[12];
    const float* xp = xin + (size_t)t*10;
    #pragma unroll
    for (int q=0;q<10;q++) in[q] = xp[q];
    in[10] = (float)h  * (1.0f/23.0f);
    in[11] = (float)wc * (1.0f/23.0f);
    #pragma unroll
    for (int c=0;c<C_;c++){
        float acc = b[c];
        #pragma unroll
        for (int q=0;q<12;q++) acc += in[q]*w[q*C_+c];
        xo[(size_t)(t/N_)*C_*N_ + (size_t)c*N_ + hw] = acc;
    }
}

// ---- fwd DFT (blocks 0..39 per (b,c)) + p_t (blocks 40..43) + transpose (44..) ----
__global__ void k_specp(const float* __restrict__ x, float* __restrict__ Xr, float* __restrict__ Xi,
                        const float* __restrict__ wk, const float* __restrict__ wb,
                        float* __restrict__ p_t,
                        const float* __restrict__ rvi, float* __restrict__ rvt){
    if (blockIdx.x >= 44){
        tr_one(rvi, rvt, TR1 + (blockIdx.x-44)*288 + (int)threadIdx.x);
        return;
    }
    if (blockIdx.x < 40){
        __shared__ float xt[576], Tr[288], Ti[288], cst[24], snt[24];
        int bc = blockIdx.x;           // b*20+c
        int tid = threadIdx.x;         // 288 threads
        if (tid < 24){
            float s, c;
            sincosf((float)tid * 0.26179938779914943654f, &s, &c);  // 2*pi/24
            cst[tid]=c; snt[tid]=s;
        }
        for (int q=tid;q<576;q+=288) xt[q] = x[(size_t)bc*576+q];
        __syncthreads();
        {   // stage 1: along w
            int h = tid/12, ky = tid%12;
            float ar=0.f, ai=0.f;
            for (int w=0;w<24;w++){
                int m = (ky*w) % 24;
                float v = xt[h*24+w];
                ar += v*cst[m];
                ai -= v*snt[m];
            }
            Tr[tid]=ar; Ti[tid]=ai;
        }
        __syncthreads();
        {   // stage 2: along h
            int kx = tid/12, ky = tid%12;
            float ar=0.f, ai=0.f;
            for (int h=0;h<24;h++){
                int m = (kx*h)%24;
                float tr=Tr[h*12+ky], ti=Ti[h*12+ky];
                float cc=cst[m], ss=snt[m];
                ar += tr*cc + ti*ss;
                ai += ti*cc - tr*ss;
            }
            Xr[(size_t)bc*288 + tid] = ar;
            Xi[(size_t)bc*288 + tid] = ai;
        }
    } else {
        __shared__ float swk[400], swb[C_];
        int tid = threadIdx.x;
        for (int q=tid;q<400;q+=288) swk[q]=wk[q];
        if (tid < C_) swb[tid]=wb[tid];
        __syncthreads();
        int t = (blockIdx.x-40)*288 + tid;            // (b,hw) < 1152
        if (t >= 2*N_) return;
        int bb = t / N_, hw = t % N_;
        float xi[C_];
        #pragma unroll
        for (int c=0;c<C_;c++) xi[c] = x[(size_t)(bb*C_+c)*N_+hw];
        float accv[C_];
        #pragma unroll
        for (int o=0;o<C_;o++){
            float acc = swb[o];
            #pragma unroll
            for (int c=0;c<C_;c++) acc += xi[c]*swk[o*C_+c];
            accv[o]=acc;
        }
        float4* dst = (float4*)(p_t + (size_t)t*C_);
        #pragma unroll
        for (int q=0;q<5;q++) dst[q] = make_float4(accv[4*q],accv[4*q+1],accv[4*q+2],accv[4*q+3]);
    }
}

// ---- mode-mix + inverse FFT (blocks 0..39 per (b,o)) + transpose (40..) ----
__global__ void k_fft_inv(const float* __restrict__ Xr, const float* __restrict__ Xi,
                          const float* __restrict__ wr, const float* __restrict__ wi,
                          float* __restrict__ a_t,
                          const float* __restrict__ rvi, float* __restrict__ rvt){
    if (blockIdx.x >= 40){
        tr_one(rvi, rvt, TR2 + (blockIdx.x-40)*576 + (int)threadIdx.x);
        return;
    }
    __shared__ float Fr[288], Fi[288], Yr[288], Yi[288], cst[24], snt[24];
    int bo = blockIdx.x; int bb = bo/20, o = bo%20;
    int tid = threadIdx.x;    // 576 threads
    if (tid < 24){
        float s, c;
        sincosf((float)tid * 0.26179938779914943654f, &s, &c);
        cst[tid]=c; snt[tid]=s;
    }
    if (tid < 288){   // mode mixing: F[kx][ky] = sum_i X[b,i,kx,ky]*W[i,o,...]
        int ky = tid%12, kx = tid/12;
        int half = (kx>=12) ? 1 : 0; int mx = kx - half*12;
        float ar=0.f, ai=0.f;
        for (int i=0;i<20;i++){
            float xr = Xr[(size_t)(bb*20+i)*288 + tid];
            float xi = Xi[(size_t)(bb*20+i)*288 + tid];
            size_t widx = ((((size_t)half*20+i)*20+o)*12+mx)*12+ky;
            float wrv = wr[widx], wiv = wi[widx];
            ar += xr*wrv - xi*wiv;
            ai += xr*wiv + xi*wrv;
        }
        Fr[tid]=ar; Fi[tid]=ai;
    }
    __syncthreads();
    if (tid < 288){  // ifft along kx
        int h = tid/12;
        float ar=0.f, ai=0.f;
        for (int kx=0;kx<24;kx++){
            int m=(kx*h)%24;
            float fr=Fr[kx*12 + (tid%12)], fi=Fi[kx*12 + (tid%12)];
            ar += fr*cst[m] - fi*snt[m];
            ai += fr*snt[m] + fi*cst[m];
        }
        Yr[tid]=ar*(1.0f/24.0f); Yi[tid]=ai*(1.0f/24.0f);
    }
    __syncthreads();
    {   // irfft along ky (imag of ky=0 discarded by irfft)
        int h = tid/24, w = tid%24;
        float acc = Yr[h*12+0];
        #pragma unroll
        for (int ky=1;ky<12;ky++){
            int m=(ky*w)%24;
            acc += 2.0f*(Yr[h*12+ky]*cst[m] - Yi[h*12+ky]*snt[m]);
        }
        a_t[((size_t)bb*N_ + tid)*C_ + o] = acc*(1.0f/24.0f);
    }
}

// ---- v_r global max (blocks 0..1151) + transpose (1152..) ----
__global__ void k_pairmax(const float* __restrict__ a_t, float* __restrict__ vmax,
                          const float* __restrict__ rvi, float* __restrict__ rvt){
    if (blockIdx.x >= 2*N_){
        tr_one(rvi, rvt, TR3 + (blockIdx.x-2*N_)*576 + (int)threadIdx.x);
        return;
    }
    __shared__ float ai[C_], wred[9];
    int bb = blockIdx.x/N_, i = blockIdx.x%N_;
    int j = threadIdx.x;                         // 576 threads
    if (j < C_) ai[j]=a_t[((size_t)bb*N_+i)*C_+j];
    __syncthreads();
    const float4* aj4 = (const float4*)(a_t + ((size_t)bb*N_+j)*C_);
    float ssv=0.f;
    #pragma unroll
    for (int q=0;q<5;q++){
        float4 av = aj4[q];
        float dv;
        dv = ai[4*q+0]-av.x; ssv += dv*dv;
        dv = ai[4*q+1]-av.y; ssv += dv*dv;
        dv = ai[4*q+2]-av.z; ssv += dv*dv;
        dv = ai[4*q+3]-av.w; ssv += dv*dv;
    }
    float m = sqrtf(ssv+1e-12f);
    #pragma unroll
    for (int off=32; off; off>>=1) m = fmaxf(m, __shfl_down(m, off, 64));
    if ((j&63)==0) wred[j>>6] = m;
    __syncthreads();
    if (j==0){
        float mm = wred[0];
        #pragma unroll
        for (int q=1;q<9;q++) mm = fmaxf(mm, wred[q]);
        atomicMax((unsigned int*)&vmax[bb], __float_as_uint(mm));   // v_r >= 0
    }
}

// -------- collision update (+ fused output head on the last layer) --------
__global__ void __launch_bounds__(256, 1)
k_vnew(const float* __restrict__ p_t, const float* __restrict__ a_t,
       const float* __restrict__ rvt, const float* __restrict__ vmax,
       const float* __restrict__ rs, int klayer,
       float* __restrict__ xout, int do_head,
       const float* __restrict__ fc1w, const float* __restrict__ fc1b,
       const float* __restrict__ fc2w, const float* __restrict__ fc2b,
       float* __restrict__ out){
    __shared__ float pi[C_], ai[C_];
    __shared__ short hlist[N_];
    __shared__ int cnts[4];
    __shared__ float wacc[4][C_];
    __shared__ float xrow[C_];
    __shared__ float psum[2];
    int bb = blockIdx.x/N_, i = blockIdx.x%N_;
    int tid = threadIdx.x;
    int wid = tid>>6, lane = tid&63;
    if (tid < C_){ pi[tid]=p_t[((size_t)bb*N_+i)*C_+tid]; ai[tid]=a_t[((size_t)bb*N_+i)*C_+tid]; }
    __syncthreads();
    float vm = vmax[bb];
    const float thr = 0.1f;                      // f32(1.0 - 0.9), JAX weak-type
    const float4* pbase = (const float4*)(p_t + (size_t)bb*N_*C_);
    const float4* abase = (const float4*)(a_t + (size_t)bb*N_*C_);

    int jb = wid*144;
    unsigned long long m0, m1, m2;
    {
        auto test = [&](int j)->bool{
            const float4* pj = pbase + j*5;
            const float4* aj = abase + j*5;
            float ssx=0.f, ssv=0.f;
            #pragma unroll
            for (int q=0;q<5;q++){
                float4 pv = pj[q], av = aj[q];
                float dx, dv;
                dx = pi[4*q+0]-pv.x; dv = ai[4*q+0]-av.x; ssx += dx*dx; ssv += dv*dv;
                dx = pi[4*q+1]-pv.y; dv = ai[4*q+1]-av.y; ssx += dx*dx; ssv += dv*dv;
                dx = pi[4*q+2]-pv.z; dv = ai[4*q+2]-av.z; ssx += dx*dx; ssv += dv*dv;
                dx = pi[4*q+3]-pv.w; dv = ai[4*q+3]-av.w; ssx += dx*dx; ssv += dv*dv;
            }
            float vrv = sqrtf(ssv+1e-12f);
            float uxv = expf(-sqrtf(ssx+1e-12f));
            return ((vrv/vm)*uxv > thr) && (j != i);
        };
        int j = jb + lane;
        m0 = __ballot(test(j));
        m1 = __ballot(test(j+64));
        bool h2 = (lane<16) ? test(jb+128+lane) : false;
        m2 = __ballot(h2);
    }
    if (lane == 0) cnts[wid] = (int)(__popcll(m0)+__popcll(m1)+__popcll(m2));
    __syncthreads();
    int off = 0;
    #pragma unroll
    for (int w=0;w<4;w++) if (w < wid) off += cnts[w];
    int nhit = cnts[0]+cnts[1]+cnts[2]+cnts[3];
    {
        unsigned long long below = (1ULL<<lane)-1ULL;
        int base = off;
        if (m0 & (1ULL<<lane)) hlist[base + __popcll(m0 & below)] = (short)(jb + lane);
        base += (int)__popcll(m0);
        if (m1 & (1ULL<<lane)) hlist[base + __popcll(m1 & below)] = (short)(jb + 64 + lane);
        base += (int)__popcll(m1);
        if (m2 & (1ULL<<lane)) hlist[base + __popcll(m2 & below)] = (short)(jb + 128 + lane);
    }
    __syncthreads();

    float s_arr[4] = { rs[0], rs[1], rs[2], rs[3] };
    float macc[C_];                              // = rA - 0.5*sum(a_q)
    #pragma unroll
    for (int c=0;c<C_;c++) macc[c]=0.f;

    for (int t=tid; t<nhit; t+=256){
        int j = hlist[t];
        float av[C_];
        {
            const float4* aj = abase + j*5;
            #pragma unroll
            for (int q=0;q<5;q++){
                float4 aa = aj[q];
                av[4*q+0]=aa.x; av[4*q+1]=aa.y; av[4*q+2]=aa.z; av[4*q+3]=aa.w;
            }
        }
        float ssv=0.f;
        #pragma unroll
        for (int c=0;c<C_;c++){ float dv = ai[c]-av[c]; ssv += dv*dv; }
        float vrij = sqrtf(ssv+1e-12f);
        float sgn = (j<i) ? 1.0f : -1.0f;        // R[c,j,i] sign
        int lo = (j<i)?j:i, hi = (j<i)?i:j;
        int pidx = lo*(2*N_-lo-1)/2 + (hi-lo-1);
        float vrs = sgn*vrij;
        float st[C_];
        {
            const float4* rp = (const float4*)(rvt + ((size_t)bb*NPAIR_ + pidx)*C_);
            #pragma unroll
            for (int q=0;q<5;q++){
                float4 rr = rp[q];
                st[4*q+0]=rr.x; st[4*q+1]=rr.y; st[4*q+2]=rr.z; st[4*q+3]=rr.w;
            }
        }
        float ssq = 0.f;
        #pragma unroll
        for (int c=0;c<C_;c++) ssq += st[c]*st[c];
        float ini = 1.0f/sqrtf(ssq);
        float orc[C_];
        #pragma unroll
        for (int c=0;c<C_;c++) orc[c] = st[c]*ini;
        for (int l=0; l<=klayer; l++){
            float s = s_arr[l];
            float nq = 0.f;
            #pragma unroll
            for (int c=0;c<C_;c++){
                float nv = st[c]*orc[c] + orc[c] + s;
                st[c] = nv; nq += nv*nv;
            }
            float inn = 1.0f/sqrtf(nq);
            #pragma unroll
            for (int c=0;c<C_;c++) st[c] *= inn;
        }
        #pragma unroll
        for (int c=0;c<C_;c++) macc[c] += vrs*st[c] - 0.5f*av[c];
    }
    #pragma unroll
    for (int off2=32; off2; off2>>=1){
        #pragma unroll
        for (int c=0;c<C_;c++) macc[c] += __shfl_xor(macc[c], off2, 64);
    }
    if (lane == 0){
        #pragma unroll
        for (int c=0;c<C_;c++) wacc[wid][c] = macc[c];
    }
    __syncthreads();
    if (!do_head){
        if (tid < C_){
            int c = tid;
            float msum = wacc[0][c]+wacc[1][c]+wacc[2][c]+wacc[3][c];
            float vi = ai[c];
            float vnew = vi + 0.5f*(float)nhit*vi + msum;
            float xn = pi[c] + vnew;
            xout[(size_t)(bb*C_+c)*N_+i] = gelu_f(xn);   // channel-major for next layer
        }
    } else {
        if (tid < C_){
            int c = tid;
            float msum = wacc[0][c]+wacc[1][c]+wacc[2][c]+wacc[3][c];
            float vi = ai[c];
            float vnew = vi + 0.5f*(float)nhit*vi + msum;
            xrow[c] = pi[c] + vnew;                      // layer 3: no gelu
        }
        __syncthreads();
        if (tid < 128){
            float h = fc1b[tid];
            #pragma unroll
            for (int c=0;c<C_;c++) h += xrow[c]*fc1w[c*128+tid];
            float g = gelu_f(h)*fc2w[tid];
            #pragma unroll
            for (int off2=32; off2; off2>>=1) g += __shfl_down(g, off2, 64);
            if (lane==0) psum[wid] = g;
        }
        __syncthreads();
        if (tid==0) out[bb*N_+i] = psum[0] + psum[1] + fc2b[0];
    }
}

extern "C" void kernel_launch(void* const* d_in, const int* in_sizes, int n_in,
                              void* d_out, int out_size, void* d_ws, size_t ws_size,
                              hipStream_t stream) {
    const float* in_x   = (const float*)d_in[0];
    // d_in[1] (v) is dead in the reference forward
    const float* fc0_w  = (const float*)d_in[2];
    const float* fc0_b  = (const float*)d_in[3];
    const float* sc_wr  = (const float*)d_in[4];
    const float* sc_wi  = (const float*)d_in[5];
    const float* w_k    = (const float*)d_in[6];
    const float* w_b    = (const float*)d_in[7];
    const float* fc1_w  = (const float*)d_in[8];
    const float* fc1_b  = (const float*)d_in[9];
    const float* fc2_w  = (const float*)d_in[10];
    const float* fc2_b  = (const float*)d_in[11];
    const float* rv_init= (const float*)d_in[12];
    const float* rv_s   = (const float*)d_in[13];
    float* out = (float*)d_out;
    float* ws  = (float*)d_ws;

    // workspace layout (floats); total 6,716,168 floats = 26.9 MB
    float* rvt   = ws;                 // 6,624,000  [b][pair][20]
    float* x_cur = ws + 6624000;       // 23040      [b][c][n]
    float* p_t   = ws + 6647040;       // 23040      [b][n][20]
    float* a_t   = ws + 6670080;       // 23040      [b][n][20]
    float* Xr    = ws + 6693120;       // 11520
    float* Xi    = ws + 6704640;       // 11520
    float* vmax  = ws + 6716160;       // 8 = [4 layers][2 batches]

    hipMemsetAsync(vmax, 0, 8*sizeof(float), stream);

    k_lift<<<5 + TR_LIFT_B, 256, 0, stream>>>(in_x, fc0_w, fc0_b, x_cur, rv_init, rvt);

    for (int k=0;k<4;k++){
        const size_t woff = (size_t)k*115200;  // 2*20*20*144
        int g_sp = (k==0) ? 44 + TR_SPEC_B : 44;
        int g_iv = (k==0) ? 40 + TR_INV_B  : 40;
        int g_pm = (k==0) ? 2*N_ + TR_PMAX_B : 2*N_;
        k_specp<<<g_sp, 288, 0, stream>>>(x_cur, Xr, Xi, w_k + k*400, w_b + k*20, p_t, rv_init, rvt);
        k_fft_inv<<<g_iv, 576, 0, stream>>>(Xr, Xi, sc_wr+woff, sc_wi+woff, a_t, rv_init, rvt);
        k_pairmax<<<g_pm, N_, 0, stream>>>(a_t, vmax + 2*k, rv_init, rvt);
        k_vnew<<<2*N_, 256, 0, stream>>>(p_t, a_t, rvt, vmax + 2*k, rv_s, k,
                                         x_cur, (k==3) ? 1 : 0,
                                         fc1_w, fc1_b, fc2_w, fc2_b, out);
    }
}